// Round 1
// baseline (119.217 us; speedup 1.0000x reference)
//
#include <hip/hip_runtime.h>
#include <hip/hip_fp16.h>

typedef float    f32x4 __attribute__((ext_vector_type(4)));
typedef _Float16 f16x2 __attribute__((ext_vector_type(2)));
typedef _Float16 f16x4 __attribute__((ext_vector_type(4)));
typedef _Float16 f16x8 __attribute__((ext_vector_type(8)));

#define BS 8
#define NN 2048
#define DK 128
#define DM 64
#define MIXOFF (1024 * DK)  // halfs between mix-0 and mix-1 rows of one batch
// log2(e) / sqrt(128): folds softmax temperature AND exp->exp2 conversion into Q
#define QSCALE 0.12751744116926208f

#define MFMA32(a, b, c) __builtin_amdgcn_mfma_f32_16x16x32_f16((a), (b), (c), 0, 0, 0)
#define EXP2(x) __builtin_amdgcn_exp2f(x)

__device__ __forceinline__ f16x2 pkrtz(float x, float y) {
  return __builtin_bit_cast(f16x2, __builtin_amdgcn_cvt_pkrtz(x, y));
}

// async global->LDS DMA, 16B per lane; no VGPR transit (allocator-proof)
__device__ __forceinline__ void load_lds16(const _Float16* g, _Float16* l) {
  __builtin_amdgcn_global_load_lds(
      (const __attribute__((address_space(1))) void*)(uintptr_t)g,
      (__attribute__((address_space(3))) void*)(uint32_t)(uintptr_t)l, 16, 0, 0);
}

// ---- fused prep: K f32->f16 (512 blk), V transpose 64x64 (512 blk), q-mean (64 blk) ----
__global__ void prep_k(const float* __restrict__ kt, _Float16* __restrict__ kh,
                       const float* __restrict__ vt, _Float16* __restrict__ vT,
                       const float* __restrict__ qt, float* __restrict__ qpart) {
  __shared__ float tile[64][65];
  __shared__ float red[256];
  int blk = blockIdx.x;
  int t = threadIdx.x;
  if (blk < 512) {
    size_t base = (size_t)blk * 4096;
#pragma unroll
    for (int j = 0; j < 4; ++j) {
      size_t i = base + j * 1024 + t * 4;
      f32x4 v = *(const f32x4*)(kt + i);
      f16x4 h;
      h[0] = (_Float16)v[0]; h[1] = (_Float16)v[1];
      h[2] = (_Float16)v[2]; h[3] = (_Float16)v[3];
      *(f16x4*)(kh + i) = h;
    }
  } else if (blk < 1024) {
    int i2 = blk - 512;
    int b = i2 >> 6;
    int rem = i2 & 63;
    int j0 = (rem & 31) * 64;   // key tile
    int c0 = (rem >> 5) * 64;   // channel tile
    int tx = t & 63, ty = t >> 6;
    const float* src = vt + ((size_t)b * NN + j0) * DK + c0;
#pragma unroll
    for (int rr = 0; rr < 16; ++rr) {
      int row = ty * 16 + rr;
      tile[row][tx] = src[(size_t)row * DK + tx];
    }
    __syncthreads();
    _Float16* dst = vT + ((size_t)b * DK + c0) * NN + j0;
    int chl = t >> 4;
    int k4 = (t & 15) * 4;
#pragma unroll
    for (int r2 = 0; r2 < 4; ++r2) {
      int ch = r2 * 16 + chl;
      f16x4 h;
      h[0] = (_Float16)tile[k4 + 0][ch]; h[1] = (_Float16)tile[k4 + 1][ch];
      h[2] = (_Float16)tile[k4 + 2][ch]; h[3] = (_Float16)tile[k4 + 3][ch];
      *(f16x4*)(dst + (size_t)ch * NN + k4) = h;
    }
  } else {
    int i = blk - 1024;
    int b = i >> 3, seg = i & 7;
    int c = t & 127, h = t >> 7;
    const float* p = qt + ((size_t)b * NN + seg * 256 + h * 128) * DK + c;
    float s = 0.f;
#pragma unroll 8
    for (int n = 0; n < 128; ++n) s += p[(size_t)n * DK];
    red[t] = s;
    __syncthreads();
    if (t < 128) qpart[(size_t)i * 128 + t] = red[t] + red[t + 128];
  }
}

// Stage step S for all 4 key-quarters (K: 4x8KB, V: 4x8KB = 64KB) into buffer
// BUF. 4096 16B units, 512 threads x 8. Same per-region unit maps as the
// R6/R7/R8-verified kh version; only the region count/bases changed.
#define STAGE(BUF, S) do {                                                 \
    _Float16* db_ = stg + (BUF) * 32768;                                   \
    load_lds16(khg + gKst + (S) * 2048,          db_ + t * 8);             \
    load_lds16(khg + gKst + 32768 + (S) * 2048,  db_ + 4096 + t * 8);      \
    load_lds16(khg + gKst + 65536 + (S) * 2048,  db_ + 8192 + t * 8);      \
    load_lds16(khg + gKst + 98304 + (S) * 2048,  db_ + 12288 + t * 8);     \
    load_lds16(vTg + gVst + (S) * 32,            db_ + 16384 + t * 8);     \
    load_lds16(vTg + gVst + 512 + (S) * 32,      db_ + 20480 + t * 8);     \
    load_lds16(vTg + gVst + 1024 + (S) * 32,     db_ + 24576 + t * 8);     \
    load_lds16(vTg + gVst + 1536 + (S) * 32,     db_ + 28672 + t * 8);     \
  } while (0)

// ---------------- main: mixture flash attention -------------------------------
// grid 256 x 512thr (1 blk/CU): b=blk&7, qb=blk>>3 (64 q/block).
// R12: wave = (m, kq): mix m, KEY-QUARTER kq (4-way in-block split-K). Each
// wave computes ALL 64 q (4 x 16q subtiles) -> 48 MFMA per 12 ds_read_b128
// (ratio 4.0; R8-lineage was 2.0). 16 steps of 128 keys (4x32), 64KB/step
// double-buffered in 128KB static LDS. K staging swizzle changed (BOTH sides)
// from (k&3)^((k>>3)<<1) to (k&3)^(((k>>3)&1)<<2): old map put the 8 lanes of
// each quad-group on only 4 of 8 bank slots (2-way conflict, half banks idle);
// new map is bijective over 8 slots -> conflict-free, and still satisfies
// swz(perm+4)==swz(perm) so kf2/kf3 reuse kA/kB. V maps unchanged (verified
// conflict-free). Split-K merge: 4 LDS phases into two parallel per-mixture
// obufs (m0->obuf0, m1->obuf1), summed at the final store; l merged via
// lbuf[8][64] in one write+read pass (never through global — R11 lesson).
__global__ __launch_bounds__(512, 2) void attn_k(const float* __restrict__ qt,
                                                 const _Float16* __restrict__ khg,
                                                 const _Float16* __restrict__ vTg,
                                                 const float* __restrict__ kern,
                                                 const float* __restrict__ qpart,
                                                 float* __restrict__ out) {
  __shared__ __align__(16) char smem[131072];
  _Float16* stg = (_Float16*)smem;  // [2][32768] halfs = 2 x 64KB staging
  const int b = blockIdx.x & 7;
  const int qb = blockIdx.x >> 3;
  const int t = threadIdx.x;
  const int wv = t >> 6;
  const int m = wv >> 2;        // mixture
  const int kq = wv & 3;        // key quarter (in-block split-K)
  const int lane = t & 63;
  const int quad = lane >> 4, l16 = lane & 15;
  const int perm = ((l16 >> 2) << 3) | (l16 & 3);
  const int bq = b * (NN * DK);
  const int bV = b * (DK * NN);

  // Q fragments: 4 subtiles x 2 chunks, f32 load + scale + pack in-register
  f16x8 qf[4][2];  // [su][chunk]
#pragma unroll
  for (int su = 0; su < 4; ++su)
#pragma unroll
    for (int c = 0; c < 2; ++c) {
      const float* qp_ = qt + bq + m * MIXOFF +
                         (qb * 64 + su * 16 + l16) * DM + quad * 8 + c * 32;
      f32x4 v0 = *(const f32x4*)qp_;
      f32x4 v1 = *(const f32x4*)(qp_ + 4);
      union { f16x8 v; f16x2 h[4]; } w;
      w.h[0] = pkrtz(v0[0] * QSCALE, v0[1] * QSCALE);
      w.h[1] = pkrtz(v0[2] * QSCALE, v0[3] * QSCALE);
      w.h[2] = pkrtz(v1[0] * QSCALE, v1[1] * QSCALE);
      w.h[3] = pkrtz(v1[2] * QSCALE, v1[3] * QSCALE);
      qf[su][c] = w.v;
    }

  // staging offsets (halfs): thread t stages K unit t / V unit t of each region
  const int mixu = t >> 8;
  const int qq8 = t & 255;
  const int rK = qq8 >> 3;
  const int uuK = (qq8 & 7) ^ ((rK & 3) ^ (((rK >> 3) & 1) << 2));  // R12 swizzle
  const int chV = t >> 2;
  const int uuV = (t & 3) ^ ((chV + (chV >> 2)) & 3);
  const int gKst = bq + mixu * MIXOFF + rK * 64 + uuK * 8;
  const int gVst = bV + chV * NN + uuV * 8;

  // LDS read offsets (halfs) within this wave's (m,kq) tiles
  const int gK = (l16 & 3) ^ (((l16 >> 2) & 1) << 2);  // == swz(perm) == swz(perm+4)
  const int hV = (l16 + (l16 >> 2)) & 3;
  const int kA = (quad ^ gK) * 8;
  const int kB = ((quad + 4) ^ gK) * 8;
  const int kbase = kq * 4096 + m * 2048 + perm * 64;
  const int vbase = 16384 + kq * 4096 + l16 * 32 + (quad ^ hV) * 8;

  const f32x4 z = {0.f, 0.f, 0.f, 0.f};
  f32x4 acc[4][8];  // [su][cc]
  float lsum[4] = {0.f, 0.f, 0.f, 0.f};
#pragma unroll
  for (int su = 0; su < 4; ++su)
#pragma unroll
    for (int cc = 0; cc < 8; ++cc) acc[su][cc] = z;

  STAGE(0, 0);
  int buf = 0;
  for (int s = 0; s < 16; ++s) {
    __syncthreads();  // tiles for step s landed; reads of buf^1 done
    if (s + 1 < 16) STAGE(buf ^ 1, s + 1);
    const _Float16* sb_ = stg + buf * 32768;
    const _Float16* kb_ = sb_ + kbase;
    f16x8 kf0 = *(const f16x8*)(kb_ + kA);
    f16x8 kf1 = *(const f16x8*)(kb_ + kB);
    f16x8 kf2 = *(const f16x8*)(kb_ + 256 + kA);
    f16x8 kf3 = *(const f16x8*)(kb_ + 256 + kB);
    f16x8 pw[4];
#pragma unroll
    for (int su = 0; su < 4; ++su) {
      f32x4 s0 = MFMA32(kf1, qf[su][1], MFMA32(kf0, qf[su][0], z));
      f32x4 s1 = MFMA32(kf3, qf[su][1], MFMA32(kf2, qf[su][0], z));
      float e0 = EXP2(s0[0]), e1 = EXP2(s0[1]), e2 = EXP2(s0[2]), e3 = EXP2(s0[3]);
      float e4 = EXP2(s1[0]), e5 = EXP2(s1[1]), e6 = EXP2(s1[2]), e7 = EXP2(s1[3]);
      lsum[su] += ((e0 + e1) + (e2 + e3)) + ((e4 + e5) + (e6 + e7));
      union { f16x8 v; f16x2 h[4]; } w;
      w.h[0] = pkrtz(e0, e1); w.h[1] = pkrtz(e2, e3);
      w.h[2] = pkrtz(e4, e5); w.h[3] = pkrtz(e6, e7);
      pw[su] = w.v;
    }
    const _Float16* vb_ = sb_ + vbase;
#pragma unroll
    for (int cc = 0; cc < 8; ++cc) {
      f16x8 vf = *(const f16x8*)(vb_ + cc * 512);
#pragma unroll
      for (int su = 0; su < 4; ++su) acc[su][cc] = MFMA32(vf, pw[su], acc[su][cc]);
    }
    buf ^= 1;
  }
  __syncthreads();  // all tile reads done; epilogue overlays staging LDS

  // ---- epilogue LDS overlay ----
  float* obuf0 = (float*)smem;                 // [64][132] floats (33792 B), m=0
  float* obuf1 = (float*)(smem + 33792);       // [64][132] floats, m=1
  float* barL = (float*)(smem + 67584);        // [8][128]
  float* lgp = (float*)(smem + 71680);
  float* exq = (float*)(smem + 71744);
  float* prp = (float*)(smem + 71808);
  float* lbuf = (float*)(smem + 71936);        // [8][64]: per-wave l partials

  // l: reduce across quads, publish per-wave partials
#pragma unroll
  for (int su = 0; su < 4; ++su) {
    lsum[su] += __shfl_xor(lsum[su], 16);
    lsum[su] += __shfl_xor(lsum[su], 32);
  }
  // prior softmax inputs (redundant per block) — interleave with l publish
  for (int e = t; e < 1024; e += 512) {
    int bb = e >> 7, c = e & 127;
    float ss = 0.f;
#pragma unroll
    for (int seg = 0; seg < 8; ++seg) ss += qpart[(size_t)(bb * 8 + seg) * 128 + c];
    barL[e] = ss * (1.0f / 2048.0f);
  }
  if (quad == 0)
#pragma unroll
    for (int su = 0; su < 4; ++su) lbuf[wv * 64 + su * 16 + l16] = lsum[su];
  __syncthreads();
  if (t < 16) {
    int mm = t >> 3, bb = t & 7;
    float ss = 0.f;
    for (int c = 0; c < DK; ++c) ss += kern[mm * DK + c] * barL[bb * 128 + c];
    lgp[t] = ss;
  }
  __syncthreads();
  if (t < 16) {
    int mm = t >> 3;
    float mx = lgp[mm * 8];
    for (int i = 1; i < 8; ++i) mx = fmaxf(mx, lgp[mm * 8 + i]);
    exq[t] = __expf(lgp[t] - mx);
  }
  __syncthreads();
  if (t < 16) {
    int mm = t >> 3;
    float sm = 0.f;
    for (int i = 0; i < 8; ++i) sm += exq[mm * 8 + i];
    prp[t] = exq[t] / sm;  // flat[m*8+b]; read as [b*2+m] (TF reshape quirk)
  }
  __syncthreads();

  const float wm = prp[b * 2 + m];
  float rr[4];
#pragma unroll
  for (int su = 0; su < 4; ++su) {
    int q = su * 16 + l16;
    rr[su] = wm / (((lbuf[(m * 4 + 0) * 64 + q] + lbuf[(m * 4 + 1) * 64 + q]) +
                    (lbuf[(m * 4 + 2) * 64 + q] + lbuf[(m * 4 + 3) * 64 + q])));
  }

  // ---- 4-phase split-K merge; m=0 and m=1 run in parallel on separate obufs --
  float* ob = (m == 0) ? obuf0 : obuf1;
  if (kq == 0) {  // seed with scaled acc
#pragma unroll
    for (int su = 0; su < 4; ++su) {
      int r_ = (su * 16 + l16) * 132 + quad * 4;
#pragma unroll
      for (int cc = 0; cc < 8; ++cc) {
        f32x4 o;
#pragma unroll
        for (int e = 0; e < 4; ++e) o[e] = acc[su][cc][e] * rr[su];
        *(f32x4*)&ob[r_ + cc * 16] = o;
      }
    }
  }
  __syncthreads();
  for (int ph = 1; ph < 4; ++ph) {
    if (kq == ph) {
#pragma unroll
      for (int su = 0; su < 4; ++su) {
        int r_ = (su * 16 + l16) * 132 + quad * 4;
#pragma unroll
        for (int cc = 0; cc < 8; ++cc) {
          f32x4 o = *(const f32x4*)&ob[r_ + cc * 16];
#pragma unroll
          for (int e = 0; e < 4; ++e) o[e] += acc[su][cc][e] * rr[su];
          *(f32x4*)&ob[r_ + cc * 16] = o;
        }
      }
    }
    __syncthreads();
  }

  const int row = t >> 3;
  const int cb = (t & 7) * 16;
  float* op = out + ((size_t)b * NN + qb * 64 + row) * DK + cb;
#pragma unroll
  for (int g = 0; g < 4; ++g) {
    f32x4 a = *(const f32x4*)&obuf0[row * 132 + cb + g * 4];
    f32x4 c = *(const f32x4*)&obuf1[row * 132 + cb + g * 4];
#pragma unroll
    for (int e = 0; e < 4; ++e) a[e] += c[e];
    *(f32x4*)(op + g * 4) = a;
  }
}

extern "C" void kernel_launch(void* const* d_in, const int* in_sizes, int n_in,
                              void* d_out, int out_size, void* d_ws, size_t ws_size,
                              hipStream_t stream) {
  const float* qt = (const float*)d_in[0];
  const float* kt = (const float*)d_in[1];
  const float* vt = (const float*)d_in[2];
  const float* kern = (const float*)d_in[3];
  float* out = (float*)d_out;

  char* ws = (char*)d_ws;
  float* qpart = (float*)(ws + 4096);         // 64*128 floats (32 KB)
  _Float16* khp = (_Float16*)(ws + 65536);    // 2M halfs (4 MB)
  _Float16* vTp = khp + (size_t)BS * NN * DK; // 2M halfs (4 MB)

  prep_k<<<dim3(1088), dim3(256), 0, stream>>>(kt, khp, vt, vTp, qt, qpart);
  attn_k<<<dim3(256), dim3(512), 0, stream>>>(qt, khp, vTp, kern, qpart, out);
}